// Round 13
// baseline (1975.312 us; speedup 1.0000x reference)
//
#include <hip/hip_runtime.h>

// ---------------------------------------------------------------------------
// Problem constants (B=16, N=128, FIN=D=512)
// ---------------------------------------------------------------------------
#define BATCH 16
#define NNODE 128
#define DIM 512
#define NP1 129              // N+1 (with virtual node)
#define EDSZ (NP1 * NP1)     // 16641 per batch
#define LSN 256
#define BIGF 3.0e38f         // sentinel (finite)

// ---------------------------------------------------------------------------
// Fused dual-input GEMM (NT)
// ---------------------------------------------------------------------------
__global__ __launch_bounds__(256) void gemm2_nt_relu(
    const float* __restrict__ X0, const float* __restrict__ X1,
    const float* __restrict__ W, const float* __restrict__ bias,
    float* __restrict__ Y0, float* __restrict__ Y1,
    int M, int N, int K) {
  const float* X = blockIdx.z ? X1 : X0;
  float* Y = blockIdx.z ? Y1 : Y0;
  __shared__ float sA[32][68];
  __shared__ float sB[32][68];
  const int tid = threadIdx.x;
  const int m0 = blockIdx.x * 64;
  const int n0 = blockIdx.y * 64;
  const int tm = tid / 16, tn = tid % 16;
  const int lr = tid >> 2;
  const int lk8 = (tid & 3) * 8;
  float acc[4][4] = {};
  for (int k0 = 0; k0 < K; k0 += 32) {
    const float* xa = X + (size_t)(m0 + lr) * K + k0 + lk8;
    const float* wb = W + (size_t)(n0 + lr) * K + k0 + lk8;
    float4 a0 = *(const float4*)(xa);
    float4 a1 = *(const float4*)(xa + 4);
    float4 b0 = *(const float4*)(wb);
    float4 b1 = *(const float4*)(wb + 4);
    sA[lk8 + 0][lr] = a0.x; sA[lk8 + 1][lr] = a0.y;
    sA[lk8 + 2][lr] = a0.z; sA[lk8 + 3][lr] = a0.w;
    sA[lk8 + 4][lr] = a1.x; sA[lk8 + 5][lr] = a1.y;
    sA[lk8 + 6][lr] = a1.z; sA[lk8 + 7][lr] = a1.w;
    sB[lk8 + 0][lr] = b0.x; sB[lk8 + 1][lr] = b0.y;
    sB[lk8 + 2][lr] = b0.z; sB[lk8 + 3][lr] = b0.w;
    sB[lk8 + 4][lr] = b1.x; sB[lk8 + 5][lr] = b1.y;
    sB[lk8 + 6][lr] = b1.z; sB[lk8 + 7][lr] = b1.w;
    __syncthreads();
#pragma unroll
    for (int k = 0; k < 32; ++k) {
      const float4 a = *(const float4*)&sA[k][tm * 4];
      const float4 b = *(const float4*)&sB[k][tn * 4];
      acc[0][0] = fmaf(a.x, b.x, acc[0][0]);
      acc[0][1] = fmaf(a.x, b.y, acc[0][1]);
      acc[0][2] = fmaf(a.x, b.z, acc[0][2]);
      acc[0][3] = fmaf(a.x, b.w, acc[0][3]);
      acc[1][0] = fmaf(a.y, b.x, acc[1][0]);
      acc[1][1] = fmaf(a.y, b.y, acc[1][1]);
      acc[1][2] = fmaf(a.y, b.z, acc[1][2]);
      acc[1][3] = fmaf(a.y, b.w, acc[1][3]);
      acc[2][0] = fmaf(a.z, b.x, acc[2][0]);
      acc[2][1] = fmaf(a.z, b.y, acc[2][1]);
      acc[2][2] = fmaf(a.z, b.z, acc[2][2]);
      acc[2][3] = fmaf(a.z, b.w, acc[2][3]);
      acc[3][0] = fmaf(a.w, b.x, acc[3][0]);
      acc[3][1] = fmaf(a.w, b.y, acc[3][1]);
      acc[3][2] = fmaf(a.w, b.z, acc[3][2]);
      acc[3][3] = fmaf(a.w, b.w, acc[3][3]);
    }
    __syncthreads();
  }
#pragma unroll
  for (int i = 0; i < 4; ++i) {
    int m = m0 + tm * 4 + i;
#pragma unroll
    for (int j = 0; j < 4; ++j) {
      int n = n0 + tn * 4 + j;
      Y[(size_t)m * N + n] = fmaxf(acc[i][j] + bias[n], 0.f);
    }
  }
}

// ---------------------------------------------------------------------------
// Virtual-node embed, both layers in ONE block (LDS hand-off).
// ---------------------------------------------------------------------------
__global__ __launch_bounds__(256) void virt_embed(
    const float* __restrict__ x,
    const float* __restrict__ W1, const float* __restrict__ b1,
    const float* __restrict__ W2, const float* __restrict__ b2,
    float* __restrict__ e_v) {
  __shared__ float sx[DIM];
  __shared__ float sh[DIM];
  for (int k = threadIdx.x; k < DIM; k += 256) sx[k] = x[k];
  __syncthreads();
  for (int n = threadIdx.x; n < DIM; n += 256) {
    const float* w = W1 + (size_t)n * DIM;
    float s = 0.f;
    for (int k = 0; k < DIM; k += 4) {
      float4 wv = *(const float4*)(w + k);
      s = fmaf(sx[k + 0], wv.x, s);
      s = fmaf(sx[k + 1], wv.y, s);
      s = fmaf(sx[k + 2], wv.z, s);
      s = fmaf(sx[k + 3], wv.w, s);
    }
    sh[n] = fmaxf(s + b1[n], 0.f);
  }
  __syncthreads();
  for (int n = threadIdx.x; n < DIM; n += 256) {
    const float* w = W2 + (size_t)n * DIM;
    float s = 0.f;
    for (int k = 0; k < DIM; k += 4) {
      float4 wv = *(const float4*)(w + k);
      s = fmaf(sh[k + 0], wv.x, s);
      s = fmaf(sh[k + 1], wv.y, s);
      s = fmaf(sh[k + 2], wv.z, s);
      s = fmaf(sh[k + 3], wv.w, s);
    }
    e_v[n] = fmaxf(s + b2[n], 0.f);
  }
}

// ---------------------------------------------------------------------------
// cdist
// ---------------------------------------------------------------------------
__global__ __launch_bounds__(256) void cdist_kernel(
    const float* __restrict__ es, const float* __restrict__ et,
    const float* __restrict__ ev, float* __restrict__ d) {
  const int b = blockIdx.z;
  const int i0 = blockIdx.x * 32;
  const int j0 = blockIdx.y * 32;
  __shared__ float sA[32][33];
  __shared__ float sB[32][33];
  const int tid = threadIdx.x;
  const int ty = tid / 16, tx = tid % 16;
  const int lr = tid / 8;
  const int lk4 = (tid % 8) * 4;
  const int gi = i0 + lr;
  const int gj = j0 + lr;
  const float* pa = (gi < NNODE) ? (es + ((size_t)b * NNODE + gi) * DIM) : ev;
  const float* pb = (gj < NNODE) ? (et + ((size_t)b * NNODE + gj) * DIM) : ev;
  float acc[2][2] = {};
  for (int k0 = 0; k0 < DIM; k0 += 32) {
    float4 av = *(const float4*)(pa + k0 + lk4);
    float4 bv = *(const float4*)(pb + k0 + lk4);
    sA[lr][lk4 + 0] = av.x; sA[lr][lk4 + 1] = av.y;
    sA[lr][lk4 + 2] = av.z; sA[lr][lk4 + 3] = av.w;
    sB[lr][lk4 + 0] = bv.x; sB[lr][lk4 + 1] = bv.y;
    sB[lr][lk4 + 2] = bv.z; sB[lr][lk4 + 3] = bv.w;
    __syncthreads();
#pragma unroll 8
    for (int k = 0; k < 32; ++k) {
      float a0 = sA[ty * 2 + 0][k], a1 = sA[ty * 2 + 1][k];
      float b0 = sB[tx * 2 + 0][k], b1 = sB[tx * 2 + 1][k];
      float d00 = a0 - b0, d01 = a0 - b1, d10 = a1 - b0, d11 = a1 - b1;
      acc[0][0] = fmaf(d00, d00, acc[0][0]);
      acc[0][1] = fmaf(d01, d01, acc[0][1]);
      acc[1][0] = fmaf(d10, d10, acc[1][0]);
      acc[1][1] = fmaf(d11, d11, acc[1][1]);
    }
    __syncthreads();
  }
#pragma unroll
  for (int i = 0; i < 2; ++i) {
    int gi2 = i0 + ty * 2 + i;
#pragma unroll
    for (int j = 0; j < 2; ++j) {
      int gj2 = j0 + tx * 2 + j;
      if (gi2 < NP1 && gj2 < NP1)
        d[(size_t)b * EDSZ + gi2 * NP1 + gj2] = sqrtf(acc[i][j]);
    }
  }
}

// ---------------------------------------------------------------------------
// Deterministic per-batch sum (fp64 tree)
// ---------------------------------------------------------------------------
__global__ __launch_bounds__(256) void batch_sum(
    const float* __restrict__ d, float* __restrict__ sums) {
  const int b = blockIdx.x;
  double s = 0.0;
  for (int idx = threadIdx.x; idx < EDSZ; idx += 256)
    s += (double)d[(size_t)b * EDSZ + idx];
  __shared__ double red[256];
  red[threadIdx.x] = s;
  __syncthreads();
  for (int off = 128; off; off >>= 1) {
    if (threadIdx.x < off) red[threadIdx.x] += red[threadIdx.x + off];
    __syncthreads();
  }
  if (threadIdx.x == 0) sums[b] = (float)red[0];
}

// ---------------------------------------------------------------------------
// normalize: edit = d / sum[b] * N*N
// ---------------------------------------------------------------------------
__global__ __launch_bounds__(256) void normalize_kernel(
    const float* __restrict__ d, const float* __restrict__ sums,
    float* __restrict__ edit) {
  int idx = blockIdx.x * 256 + threadIdx.x;
  if (idx < BATCH * EDSZ) {
    int b = idx / EDSZ;
    edit[idx] = d[idx] / sums[b] * (float)(NNODE * NNODE);
  }
}

// ---------------------------------------------------------------------------
// build_D: dense collapsed 128x128 LSAP cost per batch, from edit.
// ---------------------------------------------------------------------------
__global__ __launch_bounds__(256) void build_D(
    const float* __restrict__ edit, float* __restrict__ Dg) {
  int idx = blockIdx.x * 256 + threadIdx.x;
  if (idx < BATCH * NNODE * NNODE) {
    const int b = idx >> 14;
    const int rc = idx & 16383;
    const int i = rc >> 7, j = rc & 127;
    const float* ec = edit + (size_t)b * EDSZ;
    Dg[idx] = fminf(ec[i * NP1 + j], ec[i * NP1 + NNODE] + ec[NNODE * NP1 + j]);
  }
}

// ---------------------------------------------------------------------------
// cross-lane helpers
// ---------------------------------------------------------------------------
__device__ __forceinline__ unsigned key_of(float m, int col) {
  return (__float_as_uint(m) & 0xFFFFFF80u) | (unsigned)col;
}

template <int CTRL>
__device__ __forceinline__ unsigned dpp_umin_step(unsigned x) {
  const unsigned o = (unsigned)__builtin_amdgcn_update_dpp(
      (int)0xFFFFFFFFu, (int)x, CTRL, 0xf, 0xf, false);
  return o < x ? o : x;
}

// per-HALF min-key: kA = min over lanes 0..31, kB = min over lanes 32..63.
__device__ __forceinline__ void half_umin_key(unsigned x, unsigned& kA,
                                              unsigned& kB) {
  x = dpp_umin_step<0x111>(x);  // row_shr:1
  x = dpp_umin_step<0x112>(x);  // row_shr:2
  x = dpp_umin_step<0x114>(x);  // row_shr:4
  x = dpp_umin_step<0x118>(x);  // row_shr:8
  x = dpp_umin_step<0x142>(x);  // row_bcast:15 (merges 16-lane rows pairwise)
  kA = (unsigned)__builtin_amdgcn_readlane((int)x, 31);
  kB = (unsigned)__builtin_amdgcn_readlane((int)x, 63);
}

__device__ __forceinline__ float fsel4(float a0, float a1, float a2, float a3,
                                       int s) {
  return (s == 0) ? a0 : (s == 1) ? a1 : (s == 2) ? a2 : a3;
}
__device__ __forceinline__ int isel4(int a0, int a1, int a2, int a3, int s) {
  return (s == 0) ? a0 : (s == 1) ? a1 : (s == 2) ? a2 : a3;
}
__device__ __forceinline__ float readlane_f32(float x, int lane) {
  return __uint_as_float(
      (unsigned)__builtin_amdgcn_readlane((int)__float_as_uint(x), lane));
}
// per-lane value = (own half ? value at laneB : value at laneA)
__device__ __forceinline__ float rl2_f32(float sel, int laneA, int laneB,
                                         int h) {
  const float a = readlane_f32(sel, laneA);
  const float b = readlane_f32(sel, laneB);
  return h ? b : a;
}

// ---------------------------------------------------------------------------
// lsap_hw: TWO chains per wave, vectorized across half-waves.
// Lanes 0..31 solve batch 2*bid (cost rows from LDS), lanes 32..63 solve
// batch 2*bid+1 (cost rows from L2/global Dg). ONE instruction stream, no
// duplication: each lane owns 4 columns + 4 rows of ITS chain; argmin is a
// per-half DPP reduction; dynamic fetches are readlane pairs + cndmask.
// Pipeline per chain: column reduction -> greedy -> reduction transfer ->
// exact SAP (fp32 op-for-op identical per chain to the validated R10 math).
// ---------------------------------------------------------------------------
__global__ __launch_bounds__(64) void lsap_hw(
    const float* __restrict__ edit, const float* __restrict__ Dg,
    float* __restrict__ Aout, float* __restrict__ geds) {
  const int bid = blockIdx.x;      // 0..7
  const int lane = threadIdx.x;
  const int h = lane >> 5;         // 0 = chain A, 1 = chain B
  const int t = lane & 31;
  const int cb = t * 4;            // 4 owned columns of own chain

  const float* DgA = Dg + (size_t)(2 * bid + 0) * (NNODE * NNODE);
  const float* DgB = Dg + (size_t)(2 * bid + 1) * (NNODE * NNODE);

  __shared__ float DL[NNODE * NNODE];  // chain A cost matrix (64 KB)
  for (int idx = lane * 4; idx < NNODE * NNODE; idx += 256)
    *(float4*)&DL[idx] = *(const float4*)&DgA[idx];
  __syncthreads();

  // row fetch: both loads unconditional, per-lane select (no exec masking)
  auto fetch_row = [&](int rv) -> float4 {  // rv: 0-based row (per-lane)
    const float4 a = *(const float4*)&DL[rv * NNODE + cb];
    const float4 b = *(const float4*)&DgB[(size_t)rv * NNODE + cb];
    float4 r;
    r.x = h ? b.x : a.x; r.y = h ? b.y : a.y;
    r.z = h ? b.z : a.z; r.w = h ? b.w : a.w;
    return r;
  };

  // per-lane state (4 cols / 4 rows of own chain)
  float u0 = 0.f, u1 = 0.f, u2 = 0.f, u3 = 0.f;
  float v0, v1, v2, v3, m0, m1, m2, m3;
  int w0 = 0, w1 = 0, w2 = 0, w3 = 0;
  int p0 = 0, p1 = 0, p2 = 0, p3 = 0;
  int x0 = 0, x1 = 0, x2 = 0, x3 = 0;

  // ---------------- Phase 1: column reduction (both chains at once) -------
  int y0 = 0, y1 = 0, y2 = 0, y3 = 0;
  {
    float c0 = BIGF, c1 = BIGF, c2 = BIGF, c3 = BIGF;
    for (int r = 0; r < NNODE; ++r) {
      const float4 f = fetch_row(r);
      if (f.x < c0) { c0 = f.x; y0 = r; }
      if (f.y < c1) { c1 = f.y; y1 = r; }
      if (f.z < c2) { c2 = f.z; y2 = r; }
      if (f.w < c3) { c3 = f.w; y3 = r; }
    }
    v0 = c0; v1 = c1; v2 = c2; v3 = c3;
  }

  // Greedy conflict-free assignment (scalar walk; both chains per step)
  unsigned long long raA0 = 0, raA1 = 0, raB0 = 0, raB1 = 0;
  for (int j = 0; j < NNODE; ++j) {
    const int jl = j >> 2, jq = j & 3;
    const int sely = isel4(y0, y1, y2, y3, jq);
    const int iA = __builtin_amdgcn_readlane(sely, jl);
    const int iB = __builtin_amdgcn_readlane(sely, 32 + jl);
    {
      const unsigned long long msk = (iA < 64) ? raA0 : raA1;
      if (!((msk >> (iA & 63)) & 1ull)) {
        if (iA < 64) raA0 |= 1ull << iA; else raA1 |= 1ull << (iA - 64);
        if (h == 0 && t == jl) {
          if (jq == 0) p0 = iA + 1; else if (jq == 1) p1 = iA + 1;
          else if (jq == 2) p2 = iA + 1; else p3 = iA + 1;
        }
        if (h == 0 && t == (iA >> 2)) {
          const int q = iA & 3;
          if (q == 0) x0 = j + 1; else if (q == 1) x1 = j + 1;
          else if (q == 2) x2 = j + 1; else x3 = j + 1;
        }
      }
    }
    {
      const unsigned long long msk = (iB < 64) ? raB0 : raB1;
      if (!((msk >> (iB & 63)) & 1ull)) {
        if (iB < 64) raB0 |= 1ull << iB; else raB1 |= 1ull << (iB - 64);
        if (h == 1 && t == jl) {
          if (jq == 0) p0 = iB + 1; else if (jq == 1) p1 = iB + 1;
          else if (jq == 2) p2 = iB + 1; else p3 = iB + 1;
        }
        if (h == 1 && t == (iB >> 2)) {
          const int q = iB & 3;
          if (q == 0) x0 = j + 1; else if (q == 1) x1 = j + 1;
          else if (q == 2) x2 = j + 1; else x3 = j + 1;
        }
      }
    }
  }

  // ---------------- Phase 1r: reduction transfer (vectorized) -------------
  for (int ii = 0; ii < NNODE; ++ii) {
    const int selx = isel4(x0, x1, x2, x3, ii & 3);
    const int xjA = __builtin_amdgcn_readlane(selx, ii >> 2);
    const int xjB = __builtin_amdgcn_readlane(selx, 32 + (ii >> 2));
    const float4 f = fetch_row(ii);
    const int xjv = h ? xjB : xjA;
    const int j1v = xjv - 1;  // -1 when row unassigned (never matches cb+q)
    float r0 = fmaxf(f.x - v0, 0.f);
    float r1 = fmaxf(f.y - v1, 0.f);
    float r2 = fmaxf(f.z - v2, 0.f);
    float r3 = fmaxf(f.w - v3, 0.f);
    if (cb + 0 == j1v) r0 = BIGF;
    if (cb + 1 == j1v) r1 = BIGF;
    if (cb + 2 == j1v) r2 = BIGF;
    if (cb + 3 == j1v) r3 = BIGF;
    const unsigned kk =
        min(min(key_of(r0, cb + 0), key_of(r1, cb + 1)),
            min(key_of(r2, cb + 2), key_of(r3, cb + 3)));
    unsigned kA, kB;
    half_umin_key(kk, kA, kB);
    const int jmA = (int)(kA & 127u), jmB = (int)(kB & 127u);
    const int jmv = h ? jmB : jmA;
    const float selr = fsel4(r0, r1, r2, r3, jmv & 3);
    const float uminv = rl2_f32(selr, jmA >> 2, 32 + (jmB >> 2), h);
    if (xjv != 0) {
      if (t == (j1v >> 2)) {
        const int q = j1v & 3;
        if (q == 0) v0 -= uminv; else if (q == 1) v1 -= uminv;
        else if (q == 2) v2 -= uminv; else v3 -= uminv;
      }
      if (t == (ii >> 2)) {
        const int q = ii & 3;
        if (q == 0) u0 = uminv; else if (q == 1) u1 = uminv;
        else if (q == 2) u2 = uminv; else u3 = uminv;
      }
    }
  }

  // ---------------- Phase 2: SAP, one free row per chain per outer step ---
  for (int outer = 0; outer < NNODE; ++outer) {
    const unsigned long long fA0 = ~raA0, fA1 = ~raA1;
    const unsigned long long fB0 = ~raB0, fB1 = ~raB1;
    const bool actA = (fA0 | fA1) != 0ull;
    const bool actB = (fB0 | fB1) != 0ull;
    if (!actA && !actB) break;
    const int iA = fA0 ? (__builtin_ctzll(fA0) + 1)
                       : (fA1 ? (64 + __builtin_ctzll(fA1) + 1) : 1);
    const int iB = fB0 ? (__builtin_ctzll(fB0) + 1)
                       : (fB1 ? (64 + __builtin_ctzll(fB1) + 1) : 1);

    unsigned cused = 0, rused = 0;
    m0 = m1 = m2 = m3 = BIGF;
    int j0A = 0, j0B = 0, i0A = iA, i0B = iB;
    bool pA = actA, pB = actB;

    for (int g = 0; g <= LSN && (pA || pB); ++g) {
      const int i0v = h ? i0B : i0A;
      const int j0v = h ? j0B : j0A;
      const bool pv = h ? pB : pA;

      // mark used: column j0 (skip dummy) and row i0 (per-lane, own chain)
      if (pv && j0v > 0 && t == ((j0v - 1) >> 2)) {
        const int q = (j0v - 1) & 3;
        cused |= 1u << q;
        if (q == 0) m0 = BIGF; else if (q == 1) m1 = BIGF;
        else if (q == 2) m2 = BIGF; else m3 = BIGF;
      }
      if (pv && t == ((i0v - 1) >> 2)) rused |= 1u << ((i0v - 1) & 3);

      // u[i0] via readlane pair
      const float uc = fsel4(u0, u1, u2, u3, (i0v - 1) & 3);
      const float u_i0 =
          rl2_f32(uc, (i0A - 1) >> 2, 32 + ((i0B - 1) >> 2), h);

      const float4 f = fetch_row(i0v - 1);

      const bool f0 = !(cused & 1u), f1 = !(cused & 2u);
      const bool f2 = !(cused & 4u), f3 = !(cused & 8u);
      {
        float cur = fmaxf(f.x - u_i0 - v0, 0.f);
        bool up = pv && f0 && (cur < m0);
        m0 = up ? cur : m0; w0 = up ? j0v : w0;
      }
      {
        float cur = fmaxf(f.y - u_i0 - v1, 0.f);
        bool up = pv && f1 && (cur < m1);
        m1 = up ? cur : m1; w1 = up ? j0v : w1;
      }
      {
        float cur = fmaxf(f.z - u_i0 - v2, 0.f);
        bool up = pv && f2 && (cur < m2);
        m2 = up ? cur : m2; w2 = up ? j0v : w2;
      }
      {
        float cur = fmaxf(f.w - u_i0 - v3, 0.f);
        bool up = pv && f3 && (cur < m3);
        m3 = up ? cur : m3; w3 = up ? j0v : w3;
      }

      const unsigned kk =
          min(min(key_of(m0, cb + 0), key_of(m1, cb + 1)),
              min(key_of(m2, cb + 2), key_of(m3, cb + 3)));
      unsigned kA, kB;
      half_umin_key(kk, kA, kB);
      const int jA = (int)(kA & 127u), jB = (int)(kB & 127u);
      const int jv = h ? jB : jA;
      const float dsel = fsel4(m0, m1, m2, m3, jv & 3);
      const float delta = rl2_f32(dsel, jA >> 2, 32 + (jB >> 2), h);

      if (pv) {
        if (!f0) v0 -= delta; else m0 = fmaxf(m0 - delta, 0.f);
        if (!f1) v1 -= delta; else m1 = fmaxf(m1 - delta, 0.f);
        if (!f2) v2 -= delta; else m2 = fmaxf(m2 - delta, 0.f);
        if (!f3) v3 -= delta; else m3 = fmaxf(m3 - delta, 0.f);
        if (rused & 1u) u0 += delta;
        if (rused & 2u) u1 += delta;
        if (rused & 4u) u2 += delta;
        if (rused & 8u) u3 += delta;
      }

      const int psel = isel4(p0, p1, p2, p3, jv & 3);
      const int pj1A = __builtin_amdgcn_readlane(psel, jA >> 2);
      const int pj1B = __builtin_amdgcn_readlane(psel, 32 + (jB >> 2));
      if (pA) { j0A = jA + 1; if (pj1A == 0) pA = false; else i0A = pj1A; }
      if (pB) { j0B = jB + 1; if (pj1B == 0) pB = false; else i0B = pj1B; }
    }

    // augment both chains in lockstep
    int jcA = actA ? j0A : 0, jcB = actB ? j0B : 0;
    for (int g = 0; g <= LSN && (jcA || jcB); ++g) {
      const int jcv = h ? jcB : jcA;
      const int jcs = (jcv == 0) ? 1 : jcv;
      const int wsel = isel4(w0, w1, w2, w3, (jcs - 1) & 3);
      const int jsA = (jcA == 0) ? 1 : jcA;
      const int jsB = (jcB == 0) ? 1 : jcB;
      const int jpA = __builtin_amdgcn_readlane(wsel, (jsA - 1) >> 2);
      const int jpB = __builtin_amdgcn_readlane(wsel, 32 + ((jsB - 1) >> 2));
      const int jpv = h ? jpB : jpA;
      const int jps = (jpv == 0) ? 1 : jpv;
      const int psel2 = isel4(p0, p1, p2, p3, (jps - 1) & 3);
      const int jqA = (jpA == 0) ? 1 : jpA;
      const int jqB = (jpB == 0) ? 1 : jpB;
      const int pvrA = __builtin_amdgcn_readlane(psel2, (jqA - 1) >> 2);
      const int pvrB = __builtin_amdgcn_readlane(psel2, 32 + ((jqB - 1) >> 2));
      const int pvA = (jpA == 0) ? iA : pvrA;
      const int pvB = (jpB == 0) ? iB : pvrB;
      const int pvv = h ? pvB : pvA;
      if (jcv != 0 && t == ((jcv - 1) >> 2)) {
        const int q = (jcv - 1) & 3;
        if (q == 0) p0 = pvv; else if (q == 1) p1 = pvv;
        else if (q == 2) p2 = pvv; else p3 = pvv;
      }
      jcA = (jcA == 0) ? 0 : jpA;
      jcB = (jcB == 0) ? 0 : jpB;
    }
    if (actA) {
      const int r = iA - 1;
      if (r < 64) raA0 |= 1ull << r; else raA1 |= 1ull << (r - 64);
    }
    if (actB) {
      const int r = iB - 1;
      if (r < 64) raB0 |= 1ull << r; else raB1 |= 1ull << (r - 64);
    }
  }

  // ---------------- emit A and geds (per-half) ----------------
  {
    const int b = 2 * bid + h;
    const float* ec = edit + (size_t)b * EDSZ;
    float* A = Aout + (size_t)b * EDSZ;
    double contrib = 0.0;
    const int pr[4] = {p0, p1, p2, p3};
#pragma unroll
    for (int q = 0; q < 4; ++q) {
      const int j = cb + q;
      const int i = pr[q] - 1;
      const float sub = ec[i * NP1 + j];
      const float di = ec[i * NP1 + NNODE] + ec[NNODE * NP1 + j];
      if (sub < di) {
        A[i * NP1 + j] = 1.f;
        contrib += (double)sub;
      } else {
        A[i * NP1 + NNODE] = 1.f;
        A[NNODE * NP1 + j] = 1.f;
        contrib += (double)di;
      }
    }
#pragma unroll
    for (int off = 16; off; off >>= 1) contrib += __shfl_xor(contrib, off);
    if (t == 0) geds[b] = (float)(contrib / 256.0);
  }
}

// ---------------------------------------------------------------------------
// launch
// ---------------------------------------------------------------------------
extern "C" void kernel_launch(void* const* d_in, const int* in_sizes, int n_in,
                              void* d_out, int out_size, void* d_ws, size_t ws_size,
                              hipStream_t stream) {
  const float* x_s  = (const float*)d_in[0];
  const float* x_t  = (const float*)d_in[1];
  const float* W1   = (const float*)d_in[2];
  const float* b1   = (const float*)d_in[3];
  const float* W2   = (const float*)d_in[4];
  const float* b2   = (const float*)d_in[5];
  const float* virt = (const float*)d_in[6];

  const int M = BATCH * NNODE;  // 2048

  float* ws    = (float*)d_ws;
  float* h_s   = ws;
  float* h_t   = h_s + (size_t)M * DIM;
  float* e_s   = h_t + (size_t)M * DIM;
  float* e_t   = e_s + (size_t)M * DIM;
  float* e_v   = e_t + (size_t)M * DIM;           // 512
  float* d_raw = e_v + DIM;                       // 16*16641
  float* sums  = d_raw + (size_t)BATCH * EDSZ;    // 16
  float* Dg    = sums + 16;                       // 16*16384

  float* Aout = (float*)d_out;
  float* edit = Aout + (size_t)BATCH * EDSZ;
  float* geds = edit + (size_t)BATCH * EDSZ;

  // zero the A region (d_out is re-poisoned before every call)
  hipMemsetAsync(Aout, 0, (size_t)BATCH * EDSZ * sizeof(float), stream);

  dim3 gblk(M / 64, DIM / 64, 2);  // (32, 8, 2)
  virt_embed<<<1, 256, 0, stream>>>(virt, W1, b1, W2, b2, e_v);
  gemm2_nt_relu<<<gblk, 256, 0, stream>>>(x_s, x_t, W1, b1, h_s, h_t, M, DIM, DIM);
  gemm2_nt_relu<<<gblk, 256, 0, stream>>>(h_s, h_t, W2, b2, e_s, e_t, M, DIM, DIM);

  cdist_kernel<<<dim3(5, 5, BATCH), 256, 0, stream>>>(e_s, e_t, e_v, d_raw);
  batch_sum<<<BATCH, 256, 0, stream>>>(d_raw, sums);
  normalize_kernel<<<(BATCH * EDSZ + 255) / 256, 256, 0, stream>>>(d_raw, sums, edit);
  build_D<<<(BATCH * NNODE * NNODE + 255) / 256, 256, 0, stream>>>(edit, Dg);
  lsap_hw<<<BATCH / 2, 64, 0, stream>>>(edit, Dg, Aout, geds);
}

// Round 14
// 813.053 us; speedup vs baseline: 2.4295x; 2.4295x over previous
//
#include <hip/hip_runtime.h>

// ---------------------------------------------------------------------------
// Problem constants (B=16, N=128, FIN=D=512)
// ---------------------------------------------------------------------------
#define BATCH 16
#define NNODE 128
#define DIM 512
#define NP1 129              // N+1 (with virtual node)
#define EDSZ (NP1 * NP1)     // 16641 per batch
#define BIGF 3.0e38f         // sentinel (finite)

// ---------------------------------------------------------------------------
// Fused dual-input GEMM (NT): Y{0,1}[m][n] = relu(sum_k X{0,1}[m][k]*W[n][k]+b[n])
// ---------------------------------------------------------------------------
__global__ __launch_bounds__(256) void gemm2_nt_relu(
    const float* __restrict__ X0, const float* __restrict__ X1,
    const float* __restrict__ W, const float* __restrict__ bias,
    float* __restrict__ Y0, float* __restrict__ Y1,
    int M, int N, int K) {
  const float* X = blockIdx.z ? X1 : X0;
  float* Y = blockIdx.z ? Y1 : Y0;
  __shared__ float sA[32][68];
  __shared__ float sB[32][68];
  const int tid = threadIdx.x;
  const int m0 = blockIdx.x * 64;
  const int n0 = blockIdx.y * 64;
  const int tm = tid / 16, tn = tid % 16;
  const int lr = tid >> 2;
  const int lk8 = (tid & 3) * 8;
  float acc[4][4] = {};
  for (int k0 = 0; k0 < K; k0 += 32) {
    const float* xa = X + (size_t)(m0 + lr) * K + k0 + lk8;
    const float* wb = W + (size_t)(n0 + lr) * K + k0 + lk8;
    float4 a0 = *(const float4*)(xa);
    float4 a1 = *(const float4*)(xa + 4);
    float4 b0 = *(const float4*)(wb);
    float4 b1 = *(const float4*)(wb + 4);
    sA[lk8 + 0][lr] = a0.x; sA[lk8 + 1][lr] = a0.y;
    sA[lk8 + 2][lr] = a0.z; sA[lk8 + 3][lr] = a0.w;
    sA[lk8 + 4][lr] = a1.x; sA[lk8 + 5][lr] = a1.y;
    sA[lk8 + 6][lr] = a1.z; sA[lk8 + 7][lr] = a1.w;
    sB[lk8 + 0][lr] = b0.x; sB[lk8 + 1][lr] = b0.y;
    sB[lk8 + 2][lr] = b0.z; sB[lk8 + 3][lr] = b0.w;
    sB[lk8 + 4][lr] = b1.x; sB[lk8 + 5][lr] = b1.y;
    sB[lk8 + 6][lr] = b1.z; sB[lk8 + 7][lr] = b1.w;
    __syncthreads();
#pragma unroll
    for (int k = 0; k < 32; ++k) {
      const float4 a = *(const float4*)&sA[k][tm * 4];
      const float4 b = *(const float4*)&sB[k][tn * 4];
      acc[0][0] = fmaf(a.x, b.x, acc[0][0]);
      acc[0][1] = fmaf(a.x, b.y, acc[0][1]);
      acc[0][2] = fmaf(a.x, b.z, acc[0][2]);
      acc[0][3] = fmaf(a.x, b.w, acc[0][3]);
      acc[1][0] = fmaf(a.y, b.x, acc[1][0]);
      acc[1][1] = fmaf(a.y, b.y, acc[1][1]);
      acc[1][2] = fmaf(a.y, b.z, acc[1][2]);
      acc[1][3] = fmaf(a.y, b.w, acc[1][3]);
      acc[2][0] = fmaf(a.z, b.x, acc[2][0]);
      acc[2][1] = fmaf(a.z, b.y, acc[2][1]);
      acc[2][2] = fmaf(a.z, b.z, acc[2][2]);
      acc[2][3] = fmaf(a.z, b.w, acc[2][3]);
      acc[3][0] = fmaf(a.w, b.x, acc[3][0]);
      acc[3][1] = fmaf(a.w, b.y, acc[3][1]);
      acc[3][2] = fmaf(a.w, b.z, acc[3][2]);
      acc[3][3] = fmaf(a.w, b.w, acc[3][3]);
    }
    __syncthreads();
  }
#pragma unroll
  for (int i = 0; i < 4; ++i) {
    int m = m0 + tm * 4 + i;
#pragma unroll
    for (int j = 0; j < 4; ++j) {
      int n = n0 + tn * 4 + j;
      Y[(size_t)m * N + n] = fmaxf(acc[i][j] + bias[n], 0.f);
    }
  }
}

// ---------------------------------------------------------------------------
// Virtual-node embed, both layers in ONE block (LDS hand-off).
// ---------------------------------------------------------------------------
__global__ __launch_bounds__(256) void virt_embed(
    const float* __restrict__ x,
    const float* __restrict__ W1, const float* __restrict__ b1,
    const float* __restrict__ W2, const float* __restrict__ b2,
    float* __restrict__ e_v) {
  __shared__ float sx[DIM];
  __shared__ float sh[DIM];
  for (int k = threadIdx.x; k < DIM; k += 256) sx[k] = x[k];
  __syncthreads();
  for (int n = threadIdx.x; n < DIM; n += 256) {
    const float* w = W1 + (size_t)n * DIM;
    float s = 0.f;
    for (int k = 0; k < DIM; k += 4) {
      float4 wv = *(const float4*)(w + k);
      s = fmaf(sx[k + 0], wv.x, s);
      s = fmaf(sx[k + 1], wv.y, s);
      s = fmaf(sx[k + 2], wv.z, s);
      s = fmaf(sx[k + 3], wv.w, s);
    }
    sh[n] = fmaxf(s + b1[n], 0.f);
  }
  __syncthreads();
  for (int n = threadIdx.x; n < DIM; n += 256) {
    const float* w = W2 + (size_t)n * DIM;
    float s = 0.f;
    for (int k = 0; k < DIM; k += 4) {
      float4 wv = *(const float4*)(w + k);
      s = fmaf(sh[k + 0], wv.x, s);
      s = fmaf(sh[k + 1], wv.y, s);
      s = fmaf(sh[k + 2], wv.z, s);
      s = fmaf(sh[k + 3], wv.w, s);
    }
    e_v[n] = fmaxf(s + b2[n], 0.f);
  }
}

// ---------------------------------------------------------------------------
// cdist: d[b][i][j] = || esrow(b,i) - etrow(b,j) ||_2
// ---------------------------------------------------------------------------
__global__ __launch_bounds__(256) void cdist_kernel(
    const float* __restrict__ es, const float* __restrict__ et,
    const float* __restrict__ ev, float* __restrict__ d) {
  const int b = blockIdx.z;
  const int i0 = blockIdx.x * 32;
  const int j0 = blockIdx.y * 32;
  __shared__ float sA[32][33];
  __shared__ float sB[32][33];
  const int tid = threadIdx.x;
  const int ty = tid / 16, tx = tid % 16;
  const int lr = tid / 8;
  const int lk4 = (tid % 8) * 4;
  const int gi = i0 + lr;
  const int gj = j0 + lr;
  const float* pa = (gi < NNODE) ? (es + ((size_t)b * NNODE + gi) * DIM) : ev;
  const float* pb = (gj < NNODE) ? (et + ((size_t)b * NNODE + gj) * DIM) : ev;
  float acc[2][2] = {};
  for (int k0 = 0; k0 < DIM; k0 += 32) {
    float4 av = *(const float4*)(pa + k0 + lk4);
    float4 bv = *(const float4*)(pb + k0 + lk4);
    sA[lr][lk4 + 0] = av.x; sA[lr][lk4 + 1] = av.y;
    sA[lr][lk4 + 2] = av.z; sA[lr][lk4 + 3] = av.w;
    sB[lr][lk4 + 0] = bv.x; sB[lr][lk4 + 1] = bv.y;
    sB[lr][lk4 + 2] = bv.z; sB[lr][lk4 + 3] = bv.w;
    __syncthreads();
#pragma unroll 8
    for (int k = 0; k < 32; ++k) {
      float a0 = sA[ty * 2 + 0][k], a1 = sA[ty * 2 + 1][k];
      float b0 = sB[tx * 2 + 0][k], b1 = sB[tx * 2 + 1][k];
      float d00 = a0 - b0, d01 = a0 - b1, d10 = a1 - b0, d11 = a1 - b1;
      acc[0][0] = fmaf(d00, d00, acc[0][0]);
      acc[0][1] = fmaf(d01, d01, acc[0][1]);
      acc[1][0] = fmaf(d10, d10, acc[1][0]);
      acc[1][1] = fmaf(d11, d11, acc[1][1]);
    }
    __syncthreads();
  }
#pragma unroll
  for (int i = 0; i < 2; ++i) {
    int gi2 = i0 + ty * 2 + i;
#pragma unroll
    for (int j = 0; j < 2; ++j) {
      int gj2 = j0 + tx * 2 + j;
      if (gi2 < NP1 && gj2 < NP1)
        d[(size_t)b * EDSZ + gi2 * NP1 + gj2] = sqrtf(acc[i][j]);
    }
  }
}

// ---------------------------------------------------------------------------
// Deterministic per-batch sum (fp64 tree)
// ---------------------------------------------------------------------------
__global__ __launch_bounds__(256) void batch_sum(
    const float* __restrict__ d, float* __restrict__ sums) {
  const int b = blockIdx.x;
  double s = 0.0;
  for (int idx = threadIdx.x; idx < EDSZ; idx += 256)
    s += (double)d[(size_t)b * EDSZ + idx];
  __shared__ double red[256];
  red[threadIdx.x] = s;
  __syncthreads();
  for (int off = 128; off; off >>= 1) {
    if (threadIdx.x < off) red[threadIdx.x] += red[threadIdx.x + off];
    __syncthreads();
  }
  if (threadIdx.x == 0) sums[b] = (float)red[0];
}

// ---------------------------------------------------------------------------
// normalize: edit = d / sum[b] * N*N
// ---------------------------------------------------------------------------
__global__ __launch_bounds__(256) void normalize_kernel(
    const float* __restrict__ d, const float* __restrict__ sums,
    float* __restrict__ edit) {
  int idx = blockIdx.x * 256 + threadIdx.x;
  if (idx < BATCH * EDSZ) {
    int b = idx / EDSZ;
    edit[idx] = d[idx] / sums[b] * (float)(NNODE * NNODE);
  }
}

// ---------------------------------------------------------------------------
// cross-lane helpers: 32-bit packed argmin on the VALU pipe.
// key = (f32 bits of nonneg value with low 7 mantissa bits replaced by col).
// Unsigned order == value order (to within 2^-17 rel; ties -> lowest col).
// Exact values recovered by readlane from the winner lane, so dual
// arithmetic stays exact (perturbation limited to pop order, ~1e-6 abs —
// far inside the validated 8e-3 robustness margin).
// ---------------------------------------------------------------------------
__device__ __forceinline__ unsigned key_of(float m, int col) {
  return (__float_as_uint(m) & 0xFFFFFF80u) | (unsigned)col;
}

template <int CTRL>
__device__ __forceinline__ unsigned dpp_umin_step(unsigned x) {
  const unsigned o = (unsigned)__builtin_amdgcn_update_dpp(
      (int)0xFFFFFFFFu, (int)x, CTRL, 0xf, 0xf, false);
  return o < x ? o : x;
}

// wave64 min-key; result broadcast (readlane 63).
__device__ __forceinline__ unsigned wave_umin_key(unsigned x) {
  x = dpp_umin_step<0x111>(x);
  x = dpp_umin_step<0x112>(x);
  x = dpp_umin_step<0x114>(x);
  x = dpp_umin_step<0x118>(x);
  x = dpp_umin_step<0x142>(x);
  x = dpp_umin_step<0x143>(x);
  return (unsigned)__builtin_amdgcn_readlane((int)x, 63);
}

// merged (min1,min2) reduction: one DPP chain carries a sorted pair.
template <int CTRL>
__device__ __forceinline__ void dpp_umin2_step(unsigned& m1, unsigned& m2) {
  const unsigned o1 = (unsigned)__builtin_amdgcn_update_dpp(
      (int)0xFFFFFFFFu, (int)m1, CTRL, 0xf, 0xf, false);
  const unsigned o2 = (unsigned)__builtin_amdgcn_update_dpp(
      (int)0xFFFFFFFFu, (int)m2, CTRL, 0xf, 0xf, false);
  const unsigned lo = m1 < o1 ? m1 : o1;
  const unsigned hi = m1 < o1 ? o1 : m1;
  const unsigned yo = m2 < o2 ? m2 : o2;
  m1 = lo;
  m2 = hi < yo ? hi : yo;
}

__device__ __forceinline__ void wave_umin2_key(unsigned a, unsigned b,
                                               unsigned& k1, unsigned& k2) {
  unsigned m1 = a < b ? a : b;
  unsigned m2 = a < b ? b : a;
  dpp_umin2_step<0x111>(m1, m2);
  dpp_umin2_step<0x112>(m1, m2);
  dpp_umin2_step<0x114>(m1, m2);
  dpp_umin2_step<0x118>(m1, m2);
  dpp_umin2_step<0x142>(m1, m2);
  dpp_umin2_step<0x143>(m1, m2);
  k1 = (unsigned)__builtin_amdgcn_readlane((int)m1, 63);
  k2 = (unsigned)__builtin_amdgcn_readlane((int)m2, 63);
}

__device__ __forceinline__ float fsel2(float a0, float a1, int s) {
  return (s == 0) ? a0 : a1;
}
__device__ __forceinline__ int isel2(int a0, int a1, int s) {
  return (s == 0) ? a0 : a1;
}
__device__ __forceinline__ float readlane_f32(float x, int lane) {
  return __uint_as_float(
      (unsigned)__builtin_amdgcn_readlane((int)__float_as_uint(x), lane));
}

// ---------------------------------------------------------------------------
// LSAPE collapsed to a dense 128x128 LSAP, full LAPJV pipeline (validated
// best — R10/R11 kernel): column reduction -> reduction transfer ->
// budget-capped augmenting row reduction -> exact SAP. ONE WAVE per batch,
// lane owns 2 columns, VALU-pipe cross-lane ops only. Serial-latency floor:
// ~3000 sequential SSP iterations x ~300-cyc dependent chain. Multi-chain
// per wave (duplication R12, half-wave vectorization R13) both regress.
// ---------------------------------------------------------------------------
__global__ __launch_bounds__(64) void lsap_kernel(
    const float* __restrict__ edit, float* __restrict__ Aout,
    float* __restrict__ geds) {
  const int b = blockIdx.x;
  const float* ec = edit + (size_t)b * EDSZ;
  float* A = Aout + (size_t)b * EDSZ;
  const int lane = threadIdx.x;
  const int cbase = lane * 2;  // first owned column (0-based), 2 per lane

  __shared__ float D[NNODE * NNODE];  // 64 KB dense collapsed cost

  // stage D = min(sub, del+ins); coalesced global reads (L2-resident)
  for (int idx = lane; idx < NNODE * NNODE; idx += 64) {
    const int i = idx >> 7, j = idx & 127;
    const float sub = ec[i * NP1 + j];
    const float di = ec[i * NP1 + NNODE] + ec[NNODE * NP1 + j];
    D[idx] = fminf(sub, di);
  }
  __syncthreads();

  // per-lane state: 2 columns (v, minv, way, p) + 2 rows (u, x=row->col+1)
  float u0 = 0.f, u1 = 0.f;
  float v0 = 0.f, v1 = 0.f;
  float m0, m1;
  int w0 = 0, w1 = 0;
  int p0 = 0, p1 = 0;
  int x0 = 0, x1 = 0;

  // ---------------- Phase 1: column reduction on dense D ----------------
  int y0 = 0, y1 = 0;
  {
    float c0 = BIGF, c1 = BIGF;
    for (int r = 0; r < NNODE; ++r) {
      const float2 f = *(const float2*)&D[r * NNODE + cbase];
      if (f.x < c0) { c0 = f.x; y0 = r; }
      if (f.y < c1) { c1 = f.y; y1 = r; }
    }
    v0 = c0; v1 = c1;
  }

  // Greedy conflict-free assignment (wave-uniform scalar walk over columns).
  unsigned long long ra0 = 0, ra1 = 0;  // assigned-row bits (0..63, 64..127)
  for (int j = 0; j < NNODE; ++j) {
    const int jl = j >> 1, jq = j & 1;
    const int i1 = __builtin_amdgcn_readlane(isel2(y0, y1, jq), jl);
    const int bit = i1 & 63;
    const unsigned long long msk = (i1 < 64) ? ra0 : ra1;
    if (!((msk >> bit) & 1ull)) {
      if (i1 < 64) ra0 |= 1ull << bit; else ra1 |= 1ull << bit;
      if (lane == jl) {
        if (jq == 0) p0 = i1 + 1;
        else p1 = i1 + 1;
      }
      if (lane == (i1 >> 1)) {
        if ((i1 & 1) == 0) x0 = j + 1;
        else x1 = j + 1;
      }
    }
  }

  // ---------------- Phase 1r: reduction transfer ----------------
  for (int ii = 0; ii < NNODE; ++ii) {
    const int xj = __builtin_amdgcn_readlane(isel2(x0, x1, ii & 1), ii >> 1);
    if (xj == 0) continue;
    const int j1 = xj - 1;
    const float2 f = *(const float2*)&D[ii * NNODE + cbase];
    float r0 = fmaxf(f.x - v0, 0.f);
    float r1 = fmaxf(f.y - v1, 0.f);
    if (cbase + 0 == j1) r0 = BIGF;
    if (cbase + 1 == j1) r1 = BIGF;
    const unsigned ka = key_of(r0, cbase + 0);
    const unsigned kb = key_of(r1, cbase + 1);
    const unsigned kmin = wave_umin_key(ka < kb ? ka : kb);
    const int jm = (int)(kmin & 127u);
    const float umin = readlane_f32(fsel2(r0, r1, jm & 1), jm >> 1);
    if (lane == (j1 >> 1)) {
      if ((j1 & 1) == 0) v0 -= umin; else v1 -= umin;
    }
    if (lane == (ii >> 1)) {
      if ((ii & 1) == 0) u0 = umin; else u1 = umin;
    }
  }

  // ---------------- Phase 1.5: augmenting row reduction (budget-capped) ----
  {
    const int nfree0 =
        NNODE - __builtin_popcountll(ra0) - __builtin_popcountll(ra1);
    const int budget = 2 * nfree0 + 8;
    for (int step = 0; step < budget; ++step) {
      const unsigned long long fm0 = ~ra0, fm1 = ~ra1;
      int i;
      if (fm0) i = __builtin_ctzll(fm0);
      else if (fm1) i = 64 + __builtin_ctzll(fm1);
      else break;

      const float2 f = *(const float2*)&D[i * NNODE + cbase];
      const float r0 = fmaxf(f.x - v0, 0.f);
      const float r1 = fmaxf(f.y - v1, 0.f);
      unsigned k1, k2;
      wave_umin2_key(key_of(r0, cbase + 0), key_of(r1, cbase + 1), k1, k2);
      const int j1 = (int)(k1 & 127u), j2 = (int)(k2 & 127u);
      const float u1v = readlane_f32(fsel2(r0, r1, j1 & 1), j1 >> 1);
      const float u2v = readlane_f32(fsel2(r0, r1, j2 & 1), j2 >> 1);

      int jt = j1;
      int i1 = __builtin_amdgcn_readlane(isel2(p0, p1, j1 & 1), j1 >> 1);
      if (u1v < u2v) {
        const float dv = u2v - u1v;
        if (lane == (j1 >> 1)) {
          if ((j1 & 1) == 0) v0 -= dv; else v1 -= dv;
        }
      } else if (i1 != 0) {
        jt = j2;
        i1 = __builtin_amdgcn_readlane(isel2(p0, p1, j2 & 1), j2 >> 1);
      }
      // assign i -> jt with exact u[i] = u2v (feasible + tight)
      if (lane == (jt >> 1)) {
        if ((jt & 1) == 0) p0 = i + 1; else p1 = i + 1;
      }
      if (lane == (i >> 1)) {
        if ((i & 1) == 0) u0 = u2v; else u1 = u2v;
      }
      if (i < 64) ra0 |= 1ull << i; else ra1 |= 1ull << (i - 64);
      if (i1 != 0) {
        const int rr = i1 - 1;
        if (rr < 64) ra0 &= ~(1ull << rr); else ra1 &= ~(1ull << (rr - 64));
        if (lane == (rr >> 1)) {  // freed row: reset dual (always feasible)
          if ((rr & 1) == 0) u0 = 0.f; else u1 = 0.f;
        }
      }
    }
  }

  // ---------------- Phase 2: SAP for each remaining free row ----------------
  for (int ii = 0; ii < NNODE; ++ii) {
    const unsigned long long amsk = (ii < 64) ? ra0 : ra1;
    if ((amsk >> (ii & 63)) & 1ull) continue;  // assigned in phase 1/1.5
    const int i = ii + 1;

    unsigned cused = 0, rused = 0;
    m0 = m1 = BIGF;
    int j0 = 0;       // current column (0 = dummy start)
    int i0 = i;       // p[0] = i
    for (int guard = 0; guard <= NNODE; ++guard) {
      // --- mark used: column j0 (skip dummy col 0) and its row i0 ---
      if (j0 > 0 && lane == ((j0 - 1) >> 1)) {
        if (((j0 - 1) & 1) == 0) { cused |= 1u; m0 = BIGF; }
        else { cused |= 2u; m1 = BIGF; }
      }
      if (lane == ((i0 - 1) >> 1)) rused |= 1u << ((i0 - 1) & 1);

      // --- broadcast u[i0] from owning lane (i0 uniform -> readlane) ---
      const float u_i0 = readlane_f32(fsel2(u0, u1, (i0 - 1) & 1), (i0 - 1) >> 1);

      // --- dense cost row: one float2 per lane ---
      const float2 f = *(const float2*)&D[(i0 - 1) * NNODE + cbase];

      // --- relax free columns; clamp >=0 keeps key ordering sound ---
      const bool f0 = !(cused & 1u), f1 = !(cused & 2u);
      {
        float cur = fmaxf(f.x - u_i0 - v0, 0.f);
        bool up = f0 && (cur < m0);
        m0 = up ? cur : m0; w0 = up ? j0 : w0;
      }
      {
        float cur = fmaxf(f.y - u_i0 - v1, 0.f);
        bool up = f1 && (cur < m1);
        m1 = up ? cur : m1; w1 = up ? j0 : w1;
      }

      // --- 32-bit key argmin; exact delta via winner readlane ---
      const unsigned ka = key_of(m0, cbase + 0);
      const unsigned kb = key_of(m1, cbase + 1);
      const unsigned kmin = wave_umin_key(ka < kb ? ka : kb);
      const int jcol = (int)(kmin & 127u);
      const float delta = readlane_f32(fsel2(m0, m1, jcol & 1), jcol >> 1);
      const int j1 = jcol + 1;

      // --- dual updates (registers only) ---
      if (!f0) v0 -= delta; else m0 = fmaxf(m0 - delta, 0.f);
      if (!f1) v1 -= delta; else m1 = fmaxf(m1 - delta, 0.f);
      if (rused & 1u) u0 += delta;
      if (rused & 2u) u1 += delta;

      // --- next (or break on free column) ---
      const int pj1 = __builtin_amdgcn_readlane(
          isel2(p0, p1, (j1 - 1) & 1), (j1 - 1) >> 1);
      j0 = j1;
      if (pj1 == 0) break;
      i0 = pj1;
    }

    // --- augment along way[] chain (uniform walk via readlane) ---
    int jc = j0;
    while (jc != 0) {
      const int cl = (jc - 1) >> 1, cq = (jc - 1) & 1;
      const int jp = __builtin_amdgcn_readlane(isel2(w0, w1, cq), cl);
      const int js = (jp == 0) ? 1 : jp;  // safe index for speculative readlane
      const int pvr = __builtin_amdgcn_readlane(
          isel2(p0, p1, (js - 1) & 1), (js - 1) >> 1);
      const int pv = (jp == 0) ? i : pvr;
      if (lane == cl) {
        if (cq == 0) p0 = pv;
        else p1 = pv;
      }
      jc = jp;
    }
  }

  // --- emit A and geds: column j assigned row p[j+1]-1; re-split branches ---
  double contrib = 0.0;
  {
    const int pr[2] = {p0, p1};
#pragma unroll
    for (int q = 0; q < 2; ++q) {
      const int j = cbase + q;
      const int i = pr[q] - 1;
      const float sub = ec[i * NP1 + j];
      const float di = ec[i * NP1 + NNODE] + ec[NNODE * NP1 + j];
      if (sub < di) {
        A[i * NP1 + j] = 1.f;
        contrib += (double)sub;
      } else {
        A[i * NP1 + NNODE] = 1.f;    // delete row i
        A[NNODE * NP1 + j] = 1.f;    // insert col j
        contrib += (double)di;
      }
    }
  }
#pragma unroll
  for (int off = 32; off; off >>= 1) contrib += __shfl_xor(contrib, off);
  if (lane == 0) geds[b] = (float)(contrib / 256.0);
}

// ---------------------------------------------------------------------------
// launch
// ---------------------------------------------------------------------------
extern "C" void kernel_launch(void* const* d_in, const int* in_sizes, int n_in,
                              void* d_out, int out_size, void* d_ws, size_t ws_size,
                              hipStream_t stream) {
  const float* x_s  = (const float*)d_in[0];
  const float* x_t  = (const float*)d_in[1];
  const float* W1   = (const float*)d_in[2];
  const float* b1   = (const float*)d_in[3];
  const float* W2   = (const float*)d_in[4];
  const float* b2   = (const float*)d_in[5];
  const float* virt = (const float*)d_in[6];

  const int M = BATCH * NNODE;  // 2048

  float* ws    = (float*)d_ws;
  float* h_s   = ws;
  float* h_t   = h_s + (size_t)M * DIM;
  float* e_s   = h_t + (size_t)M * DIM;
  float* e_t   = e_s + (size_t)M * DIM;
  float* e_v   = e_t + (size_t)M * DIM;           // 512
  float* d_raw = e_v + DIM;                       // 16*16641
  float* sums  = d_raw + (size_t)BATCH * EDSZ;    // 16

  float* Aout = (float*)d_out;
  float* edit = Aout + (size_t)BATCH * EDSZ;
  float* geds = edit + (size_t)BATCH * EDSZ;

  // zero the A output region (d_out is re-poisoned before every call)
  hipMemsetAsync(Aout, 0, (size_t)BATCH * EDSZ * sizeof(float), stream);

  dim3 gblk(M / 64, DIM / 64, 2);  // (32, 8, 2)
  virt_embed<<<1, 256, 0, stream>>>(virt, W1, b1, W2, b2, e_v);
  gemm2_nt_relu<<<gblk, 256, 0, stream>>>(x_s, x_t, W1, b1, h_s, h_t, M, DIM, DIM);
  gemm2_nt_relu<<<gblk, 256, 0, stream>>>(h_s, h_t, W2, b2, e_s, e_t, M, DIM, DIM);

  cdist_kernel<<<dim3(5, 5, BATCH), 256, 0, stream>>>(e_s, e_t, e_v, d_raw);
  batch_sum<<<BATCH, 256, 0, stream>>>(d_raw, sums);
  normalize_kernel<<<(BATCH * EDSZ + 255) / 256, 256, 0, stream>>>(d_raw, sums, edit);
  lsap_kernel<<<BATCH, 64, 0, stream>>>(edit, Aout, geds);
}